// Round 3
// baseline (433.058 us; speedup 1.0000x reference)
//
#include <hip/hip_runtime.h>
#include <hip/hip_bf16.h>
#include <math.h>

using bf16 = __hip_bfloat16;
typedef __bf16 bf16x8 __attribute__((ext_vector_type(8)));
typedef float f32x4 __attribute__((ext_vector_type(4)));

#define SEQ 2048
#define DIM 1024
#define NH 16
#define HDIM 64
#define BATCH 2

// async global->LDS, 16B per lane; LDS dest = base + lane*16 (wave-uniform base)
__device__ __forceinline__ void load_lds16(const bf16* g, bf16* l) {
  __builtin_amdgcn_global_load_lds((__attribute__((address_space(1))) void*)g,
                                   (__attribute__((address_space(3))) void*)l, 16, 0, 0);
}

// ---------------- convert+transpose: in f32 [R][C] -> out bf16 [C][R] ----------------
__global__ __launch_bounds__(256) void transpose_k(const float* __restrict__ in,
                                                   bf16* __restrict__ out, int R, int C) {
  __shared__ float tile[32][33];
  int c0 = blockIdx.x * 32, r0 = blockIdx.y * 32;
  int tx = threadIdx.x, ty = threadIdx.y;  // (32,8)
#pragma unroll
  for (int j = 0; j < 4; ++j)
    tile[ty + 8 * j][tx] = in[(size_t)(r0 + ty + 8 * j) * C + c0 + tx];
  __syncthreads();
#pragma unroll
  for (int j = 0; j < 4; ++j)
    out[(size_t)(c0 + ty + 8 * j) * R + r0 + tx] = __float2bfloat16(tile[tx][ty + 8 * j]);
}

// ---------------- layernorm (torch-style: unbiased std, /(std+eps)); f32 in, bf16 out ----
__global__ __launch_bounds__(256) void ln_k(const float* __restrict__ x,
                                            const float* __restrict__ w,
                                            const float* __restrict__ bb,
                                            bf16* __restrict__ out) {
  int row = blockIdx.x, tid = threadIdx.x;
  int wid = tid >> 6, lane = tid & 63;
  const float* xr = x + (size_t)row * DIM;
  float v[4];
#pragma unroll
  for (int j = 0; j < 4; ++j) v[j] = xr[tid + 256 * j];
  float s = v[0] + v[1] + v[2] + v[3];
#pragma unroll
  for (int m = 1; m < 64; m <<= 1) s += __shfl_xor(s, m, 64);
  __shared__ float red[8];
  if (lane == 0) red[wid] = s;
  __syncthreads();
  float mean = (red[0] + red[1] + red[2] + red[3]) * (1.f / DIM);
  float q = 0.f;
#pragma unroll
  for (int j = 0; j < 4; ++j) {
    v[j] -= mean;
    q += v[j] * v[j];
  }
#pragma unroll
  for (int m = 1; m < 64; m <<= 1) q += __shfl_xor(q, m, 64);
  if (lane == 0) red[4 + wid] = q;
  __syncthreads();
  float ssq = red[4] + red[5] + red[6] + red[7];
  float sd = sqrtf(ssq / (float)(DIM - 1));
  float inv = 1.f / (sd + 1e-5f);
#pragma unroll
  for (int j = 0; j < 4; ++j) {
    int c = tid + 256 * j;
    float y = w[c] * (v[j] * inv) + bb[c];
    out[(size_t)row * DIM + c] = __float2bfloat16(y);
  }
}

// ---------------- GEMM: C[M,N] = A[M,K](bf16) @ Bt[N,K](bf16)^T + bias(f32) ----------------
// 2-deep pipelined double-buffered K-loop: counted s_waitcnt vmcnt(N) + RAW s_barrier
// (never drain vmcnt to 0 in steady state -> staged loads stay in flight across barriers).
// global_load_lds(16B) into XOR-swizzled unpadded LDS. XCD-chunked block swizzle (nwg%8==0).
// TM=128: 128x128 tile (qkv, fc). TM=64: 64x128 tile (N=1024 GEMMs).
// mode 0: split qkv; q,k -> [B,H,S,HD]; v -> TRANSPOSED [B,H,HD,S]
// mode 1: x2out(f32) = residf(f32) + acc + bias
// mode 2: o0(bf16) = gelu(acc + bias)
// mode 3: outf(f32) = x2in(f32) + acc + bias     <- final output fp32
template <int TM>
__global__ __launch_bounds__(256) void gemm_k(
    const bf16* __restrict__ A, const bf16* __restrict__ Bt, const float* __restrict__ bias,
    int M, int N, int K, int mode,
    bf16* __restrict__ o0, bf16* __restrict__ o1, bf16* __restrict__ o2,
    const float* __restrict__ residf, float* __restrict__ x2out, const float* __restrict__ x2in,
    float* __restrict__ outf) {
  constexpr int MT = TM / 32;   // m-fragments per wave
  constexpr int ACH = TM / 8;   // 1KB staging chunks per A buffer
  __shared__ bf16 As[2][TM * 64];
  __shared__ bf16 Bs[2][128 * 64];
  int tid = threadIdx.x;
  int wid = tid >> 6, lane = tid & 63, quad = lane >> 4, l15 = lane & 15;
  int wm = wid >> 1, wn = wid & 1;
  // bijective XCD-chunked swizzle: concurrent blocks on one XCD share an A-panel
  int nwg = gridDim.x * gridDim.y;
  int flat = blockIdx.y * gridDim.x + blockIdx.x;
  int swz = (flat & 7) * (nwg >> 3) + (flat >> 3);
  int m0 = (swz / gridDim.x) * TM, n0 = (swz % gridDim.x) * 128;
  int rsub = lane >> 3;          // row within an 8-row chunk
  int c8 = (lane & 7) ^ rsub;    // swizzled global column-chunk this lane fetches
  f32x4 acc[MT][4] = {};
  const int nt = K >> 6;

  auto stage = [&](int t, int buf) {
    int k0 = t * 64;
#pragma unroll
    for (int it = 0; it < ACH / 4; ++it) {
      int c = wid * (ACH / 4) + it;
      int row = c * 8 + rsub;
      load_lds16(A + (size_t)(m0 + row) * K + k0 + c8 * 8, &As[buf][c * 512]);
    }
#pragma unroll
    for (int it = 0; it < 4; ++it) {
      int c = wid * 4 + it;
      int row = c * 8 + rsub;
      load_lds16(Bt + (size_t)(n0 + row) * K + k0 + c8 * 8, &Bs[buf][c * 512]);
    }
  };

  stage(0, 0);
  stage(1, 1);

  for (int t = 0; t < nt; ++t) {
    int cur = t & 1;
    // wait: stage(t) landed; stage(t+1)'s LPS loads may stay in flight
    if (t + 1 < nt) {
      if constexpr (TM == 128) asm volatile("s_waitcnt vmcnt(8)" ::: "memory");
      else                     asm volatile("s_waitcnt vmcnt(6)" ::: "memory");
    } else {
      asm volatile("s_waitcnt vmcnt(0)" ::: "memory");
    }
    __builtin_amdgcn_sched_barrier(0);
    __builtin_amdgcn_s_barrier();  // raw: no vmcnt drain
    __builtin_amdgcn_sched_barrier(0);
    const bf16* Ac = As[cur];
    const bf16* Bc = Bs[cur];
#pragma unroll
    for (int ks = 0; ks < 2; ++ks) {
      bf16x8 af[MT], bfr[4];
#pragma unroll
      for (int mt = 0; mt < MT; ++mt) {
        int r = wm * (MT * 16) + mt * 16 + l15;
        af[mt] = *(const bf16x8*)&Ac[r * 64 + ((ks * 4 + quad) ^ (r & 7)) * 8];
      }
#pragma unroll
      for (int nt2 = 0; nt2 < 4; ++nt2) {
        int r = wn * 64 + nt2 * 16 + l15;
        bfr[nt2] = *(const bf16x8*)&Bc[r * 64 + ((ks * 4 + quad) ^ (r & 7)) * 8];
      }
      __builtin_amdgcn_s_setprio(1);
#pragma unroll
      for (int mt = 0; mt < MT; ++mt)
#pragma unroll
        for (int nt2 = 0; nt2 < 4; ++nt2)
          acc[mt][nt2] =
              __builtin_amdgcn_mfma_f32_16x16x32_bf16(af[mt], bfr[nt2], acc[mt][nt2], 0, 0, 0);
      __builtin_amdgcn_s_setprio(0);
    }
    __builtin_amdgcn_sched_barrier(0);
    __builtin_amdgcn_s_barrier();  // raw: all waves done reading buf[cur]
    __builtin_amdgcn_sched_barrier(0);
    if (t + 2 < nt) stage(t + 2, cur);
  }

#pragma unroll
  for (int mt = 0; mt < MT; ++mt) {
#pragma unroll
    for (int nt = 0; nt < 4; ++nt) {
      int col = n0 + wn * 64 + nt * 16 + l15;
      float bv = bias[col];
      int row_base = m0 + wm * (MT * 16) + mt * 16 + quad * 4;
      if (mode == 0) {
        int which = col >> 10, d = col & 1023, hh = d >> 6, dd = d & 63;
        int b = row_base >> 11, s2 = row_base & 2047;
        if (which == 2) {
          unsigned short pk[4];
#pragma unroll
          for (int r = 0; r < 4; ++r)
            pk[r] = __bfloat16_as_ushort(__float2bfloat16(acc[mt][nt][r] + bv));
          *(uint2*)&o2[(((size_t)b * NH + hh) * HDIM + dd) * SEQ + s2] = *(uint2*)pk;
        } else {
          bf16* dst = which == 0 ? o0 : o1;
#pragma unroll
          for (int r = 0; r < 4; ++r)
            dst[(((size_t)b * NH + hh) * SEQ + s2 + r) * HDIM + dd] =
                __float2bfloat16(acc[mt][nt][r] + bv);
        }
      } else {
#pragma unroll
        for (int r = 0; r < 4; ++r) {
          int row = row_base + r;
          float val = acc[mt][nt][r] + bv;
          if (mode == 1) {
            size_t i = (size_t)row * N + col;
            x2out[i] = residf[i] + val;
          } else if (mode == 2) {
            float t2 = val;
            // gelu via sigmoid: 0.5t(1+tanh(u)) = t * sigmoid(2u); saturates clean at +-inf
            float u = 0.7978845608028654f * (t2 + 0.044715f * t2 * t2 * t2);
            float g = t2 / (1.f + __expf(-2.f * u));
            o0[(size_t)row * N + col] = __float2bfloat16(g);
          } else {
            size_t i = (size_t)row * N + col;
            outf[i] = x2in[i] + val;
          }
        }
      }
    }
  }
}

// ---------------- V suffix-sum: suf[bh][d][q] = sum_{k>q} Vt[bh][d][k] (fp32) ----------------
__global__ __launch_bounds__(256) void sufv_k(const bf16* __restrict__ vt,
                                              float* __restrict__ suf) {
  int row = blockIdx.x;  // (b*NH+h)*HDIM + d
  const bf16* src = vt + (size_t)row * SEQ;
  float* dst = suf + (size_t)row * SEQ;
  int tid = threadIdx.x;
  float v[8];
  float s = 0.f;
#pragma unroll
  for (int j = 0; j < 8; ++j) {
    v[j] = __bfloat162float(src[tid * 8 + j]);
    s += v[j];
  }
  __shared__ float sc[256];
  sc[tid] = s;
  __syncthreads();
  for (int off = 1; off < 256; off <<= 1) {
    float add = (tid + off < 256) ? sc[tid + off] : 0.f;
    __syncthreads();
    sc[tid] += add;
    __syncthreads();
  }
  float run = (tid < 255) ? sc[tid + 1] : 0.f;  // exclusive suffix carry
#pragma unroll
  for (int j = 7; j >= 0; --j) {
    dst[tid * 8 + j] = run;
    run += v[j];
  }
}

// Ps swizzle: chunk ^ ((row&7) ^ (((row>>3)&1)<<1)) — bijective per row; makes both the
// 16 scalar u16 writes (8 distinct chunks per instr) and the b128 reads 2-way max (free).
__device__ __forceinline__ int pswz(int row) { return (row & 7) ^ (((row >> 3) & 1) << 1); }

// ---------------- attention: triangular, fixed-ref softmax, dbuf + swizzled, 4 blocks/CU ----
// LDS = K/V dbuf (32KB) + Ps[64][64] swizzled (8KB) = 40960B exactly -> 4 blocks/CU.
// Q fragments loaded straight global->reg (loop-invariant). Diagonal tile peeled out of the
// main loop (no mask VALU in steady state). ONE barrier per tile; prefetch K/V (load_lds)
// and rel indices (regs) for tile kt+1 during tile kt. setprio(1) around MFMA clusters.
// Masked keys (logit 0): l += cnt, O += SufV (exp(0)=1) in the epilogue.
__global__ __launch_bounds__(256) void attn_k(const bf16* __restrict__ q,
                                              const bf16* __restrict__ k,
                                              const bf16* __restrict__ v,
                                              const int* __restrict__ rel,
                                              const float* __restrict__ rel_emb,
                                              const float* __restrict__ suf,
                                              bf16* __restrict__ out) {
  int h = blockIdx.x;
  int qt = (SEQ / 64 - 1) - blockIdx.y;  // heavy blocks first
  int b = blockIdx.z;
  int tid = threadIdx.x;
  int wid = tid >> 6, lane = tid & 63, quad = lane >> 4, l15 = lane & 15;

  __shared__ __align__(16) char SM[40960];
  bf16* Kb = (bf16*)SM;                        // [2][64][64] swizzled chunks
  bf16* Vb = (bf16*)(SM + 16384);              // [2][64][64] swizzled ([d][key])
  bf16* Ps = (bf16*)(SM + 32768);              // [64][64] swizzled
  float(*SufLds)[68] = (float(*)[68])SM;       // epilogue alias over K/V dbuf (17408 B)

  const size_t bh = (size_t)b * NH + h;
  const bf16* qb = q + (bh * SEQ + (size_t)qt * 64) * HDIM;
  const bf16* kb0 = k + bh * SEQ * HDIM;
  const bf16* vt0 = v + bh * (size_t)HDIM * SEQ;

  // per-lane copy of 0.125*rel_emb[lane][h]; looked up via __shfl (ds_bpermute)
  float rv = 0.125f * rel_emb[lane * NH + h];

  int rsub = lane >> 3;
  int c8 = (lane & 7) ^ rsub;  // pre-swizzled source chunk -> linear LDS dest

  // loop-invariant Q fragments: straight global->reg (row wid*16+l15, 16B per ks-half)
  bf16x8 aq[2];
#pragma unroll
  for (int ks = 0; ks < 2; ++ks)
    aq[ks] = *(const bf16x8*)(qb + (size_t)(wid * 16 + l15) * HDIM + ks * 32 + quad * 8);

  // prologue staging: first K/V tile
#pragma unroll
  for (int it = 0; it < 2; ++it) {
    int c = wid * 2 + it;
    int row = c * 8 + rsub;
    load_lds16(kb0 + (size_t)row * HDIM + c8 * 8, &Kb[c * 512]);
    load_lds16(vt0 + (size_t)row * SEQ + c8 * 8, &Vb[c * 512]);
  }

  const int* relq = rel + (size_t)b * SEQ * SEQ + (size_t)qt * 64 * SEQ;
  const int* rp[4];
#pragma unroll
  for (int r = 0; r < 4; ++r) rp[r] = relq + (size_t)(wid * 16 + quad * 4 + r) * SEQ;

  // rel indices for tile 0 (quad-coalesced 64B segments)
  int ridx[4][4];
#pragma unroll
  for (int nt = 0; nt < 4; ++nt)
#pragma unroll
    for (int r = 0; r < 4; ++r) ridx[nt][r] = rp[r][nt * 16 + l15];

  __syncthreads();  // drain prologue staging

  const int q_base = qt * 64 + wid * 16 + quad * 4;
  const int prow_w = wid * 16 + quad * 4;       // write-side Ps row base
  const int prow_r = wid * 16 + l15;            // read-side Ps row
  const int psw_r = pswz(prow_r);
  float l_part[4] = {0.f, 0.f, 0.f, 0.f};
  f32x4 o_acc[4] = {};

  for (int kt = 0; kt < qt; ++kt) {
    int cur = kt & 1;

    // ---- prefetch tile kt+1 (overlaps with compute below; drained by end barrier) ----
    int ridx2[4][4];
    {
      bf16* Kd = Kb + (cur ^ 1) * 4096;
      bf16* Vd = Vb + (cur ^ 1) * 4096;
#pragma unroll
      for (int it = 0; it < 2; ++it) {
        int c = wid * 2 + it;
        int row = c * 8 + rsub;
        load_lds16(kb0 + (size_t)((kt + 1) * 64 + row) * HDIM + c8 * 8, &Kd[c * 512]);
        load_lds16(vt0 + (size_t)row * SEQ + (kt + 1) * 64 + c8 * 8, &Vd[c * 512]);
      }
#pragma unroll
      for (int nt = 0; nt < 4; ++nt)
#pragma unroll
        for (int r = 0; r < 4; ++r) ridx2[nt][r] = rp[r][(kt + 1) * 64 + nt * 16 + l15];
    }

    const bf16* Ksb = Kb + cur * 4096;
    const bf16* Vtb = Vb + cur * 4096;

    // ---- S = Q K^T (swizzled K reads, conflict-free) ----
    f32x4 sacc[4] = {};
    __builtin_amdgcn_s_setprio(1);
#pragma unroll
    for (int ks = 0; ks < 2; ++ks) {
#pragma unroll
      for (int nt = 0; nt < 4; ++nt) {
        bf16x8 bfr = *(const bf16x8*)&Ksb[(nt * 16 + l15) * 64 + ((ks * 4 + quad) ^ (l15 & 7)) * 8];
        sacc[nt] = __builtin_amdgcn_mfma_f32_16x16x32_bf16(aq[ks], bfr, sacc[nt], 0, 0, 0);
      }
    }
    __builtin_amdgcn_s_setprio(0);

    // ---- p = exp(s * relv[ridx]); no mask in steady state ----
#pragma unroll
    for (int nt = 0; nt < 4; ++nt) {
#pragma unroll
      for (int r = 0; r < 4; ++r) {
        float m = __shfl(rv, ridx[nt][r], 64);
        float p = __expf(sacc[nt][r] * m);
        l_part[r] += p;
        int row = prow_w + r;
        int sw = (nt * 2 + (l15 >> 3)) ^ pswz(row);
        Ps[row * 64 + sw * 8 + (l15 & 7)] = __float2bfloat16(p);
      }
    }

    // ---- O += P V (Ps rows are wave-private: no barrier needed between write & read) ----
    __builtin_amdgcn_s_setprio(1);
#pragma unroll
    for (int ks = 0; ks < 2; ++ks) {
      bf16x8 af = *(const bf16x8*)&Ps[prow_r * 64 + ((ks * 4 + quad) ^ psw_r) * 8];
#pragma unroll
      for (int nt = 0; nt < 4; ++nt) {
        bf16x8 bfr = *(const bf16x8*)&Vtb[(nt * 16 + l15) * 64 + ((ks * 4 + quad) ^ (l15 & 7)) * 8];
        o_acc[nt] = __builtin_amdgcn_mfma_f32_16x16x32_bf16(af, bfr, o_acc[nt], 0, 0, 0);
      }
    }
    __builtin_amdgcn_s_setprio(0);

    __syncthreads();  // vmcnt drain: kt+1 staging landed; lgkm drain: this tile's reads done

#pragma unroll
    for (int nt = 0; nt < 4; ++nt)
#pragma unroll
      for (int r = 0; r < 4; ++r) ridx[nt][r] = ridx2[nt][r];
  }

  // ---- diagonal tile kt == qt (peeled: causal mask applies here only) ----
  {
    int cur = qt & 1;
    const bf16* Ksb = Kb + cur * 4096;
    const bf16* Vtb = Vb + cur * 4096;

    f32x4 sacc[4] = {};
    __builtin_amdgcn_s_setprio(1);
#pragma unroll
    for (int ks = 0; ks < 2; ++ks) {
#pragma unroll
      for (int nt = 0; nt < 4; ++nt) {
        bf16x8 bfr = *(const bf16x8*)&Ksb[(nt * 16 + l15) * 64 + ((ks * 4 + quad) ^ (l15 & 7)) * 8];
        sacc[nt] = __builtin_amdgcn_mfma_f32_16x16x32_bf16(aq[ks], bfr, sacc[nt], 0, 0, 0);
      }
    }
    __builtin_amdgcn_s_setprio(0);

#pragma unroll
    for (int nt = 0; nt < 4; ++nt) {
#pragma unroll
      for (int r = 0; r < 4; ++r) {
        float m = __shfl(rv, ridx[nt][r], 64);
        float p = __expf(sacc[nt][r] * m);
        int k_abs = qt * 64 + nt * 16 + l15;
        if (k_abs > q_base + r) p = 0.f;
        l_part[r] += p;
        int row = prow_w + r;
        int sw = (nt * 2 + (l15 >> 3)) ^ pswz(row);
        Ps[row * 64 + sw * 8 + (l15 & 7)] = __float2bfloat16(p);
      }
    }

    __builtin_amdgcn_s_setprio(1);
#pragma unroll
    for (int ks = 0; ks < 2; ++ks) {
      bf16x8 af = *(const bf16x8*)&Ps[prow_r * 64 + ((ks * 4 + quad) ^ psw_r) * 8];
#pragma unroll
      for (int nt = 0; nt < 4; ++nt) {
        bf16x8 bfr = *(const bf16x8*)&Vtb[(nt * 16 + l15) * 64 + ((ks * 4 + quad) ^ (l15 & 7)) * 8];
        o_acc[nt] = __builtin_amdgcn_mfma_f32_16x16x32_bf16(af, bfr, o_acc[nt], 0, 0, 0);
      }
    }
    __builtin_amdgcn_s_setprio(0);

    __syncthreads();  // all LDS reads done before SufLds aliases K/V dbuf
  }

  // ---- epilogue: reduce l across the 16 lanes holding each row, add masked term ----
#pragma unroll
  for (int r = 0; r < 4; ++r)
#pragma unroll
    for (int m = 1; m < 16; m <<= 1) l_part[r] += __shfl_xor(l_part[r], m, 64);

  const float* sufb = suf + bh * (size_t)HDIM * SEQ + (size_t)qt * 64;
#pragma unroll
  for (int p = 0; p < 4; ++p) {
    int idx = p * 256 + tid;
    int d = idx >> 4, qq = idx & 15;
    *(float4*)&SufLds[d][qq * 4] = *(const float4*)(sufb + (size_t)d * SEQ + qq * 4);
  }
  __syncthreads();

#pragma unroll
  for (int nt = 0; nt < 4; ++nt) {
    int d = nt * 16 + l15;
#pragma unroll
    for (int r = 0; r < 4; ++r) {
      int row = q_base + r;
      int cnt = (SEQ - 1) - row;  // # masked keys, each contributing exp(0)=1
      float l = l_part[r] + (float)cnt;
      int q_local = wid * 16 + quad * 4 + r;
      float ov = (o_acc[nt][r] + SufLds[d][q_local]) / l;
      out[((size_t)b * SEQ + row) * DIM + h * HDIM + d] = __float2bfloat16(ov);
    }
  }
}

// ---------------- launcher ----------------
extern "C" void kernel_launch(void* const* d_in, const int* in_sizes, int n_in,
                              void* d_out, int out_size, void* d_ws, size_t ws_size,
                              hipStream_t stream) {
  const float* x = (const float*)d_in[0];
  const int* rel = (const int*)d_in[1];
  const float* ln1w = (const float*)d_in[2];
  const float* ln1b = (const float*)d_in[3];
  const float* Wqkv = (const float*)d_in[4];
  const float* bqkv = (const float*)d_in[5];
  const float* Wo = (const float*)d_in[6];
  const float* bo = (const float*)d_in[7];
  const float* rel_emb = (const float*)d_in[8];
  const float* ln2w = (const float*)d_in[9];
  const float* ln2b = (const float*)d_in[10];
  const float* Wfc = (const float*)d_in[11];
  const float* bfc = (const float*)d_in[12];
  const float* Wp = (const float*)d_in[13];
  const float* bp = (const float*)d_in[14];
  float* outp = (float*)d_out;  // reference output dtype is float32

  char* ws = (char*)d_ws;
  const size_t MB = 1u << 20;
  bf16* h = (bf16*)(ws + 0);           // ln1 out -> attn out
  bf16* qb = (bf16*)(ws + 8 * MB);     // q -> ln2 out
  bf16* kb = (bf16*)(ws + 16 * MB);    // k -> wfcT
  bf16* vb = (bf16*)(ws + 24 * MB);    // v transposed [B,H,HD,S] -> wpT
  float* x2 = (float*)(ws + 32 * MB);  // early: V suffix-sums; later: residual stream
  float* suf = (float*)(ws + 32 * MB);
  bf16* fcb = (bf16*)(ws + 48 * MB);   // gelu(fc); early: wqkvT@48, woT@54
  bf16* wqkvT = (bf16*)(ws + 48 * MB);
  bf16* woT = (bf16*)(ws + 54 * MB);
  bf16* wfcT = (bf16*)(ws + 16 * MB);
  bf16* wpT = (bf16*)(ws + 24 * MB);

  dim3 tb(32, 8);
  transpose_k<<<dim3(3072 / 32, 1024 / 32), tb, 0, stream>>>(Wqkv, wqkvT, 1024, 3072);
  transpose_k<<<dim3(1024 / 32, 1024 / 32), tb, 0, stream>>>(Wo, woT, 1024, 1024);

  ln_k<<<BATCH * SEQ, 256, 0, stream>>>(x, ln1w, ln1b, h);

  gemm_k<128><<<dim3(3072 / 128, 4096 / 128), 256, 0, stream>>>(
      h, wqkvT, bqkv, BATCH * SEQ, 3072, 1024, 0, qb, kb, vb, nullptr, nullptr, nullptr,
      nullptr);

  sufv_k<<<BATCH * NH * HDIM, 256, 0, stream>>>(vb, suf);

  attn_k<<<dim3(NH, SEQ / 64, BATCH), 256, 0, stream>>>(qb, kb, vb, rel, rel_emb, suf, h);

  gemm_k<64><<<dim3(1024 / 128, 4096 / 64), 256, 0, stream>>>(
      h, woT, bo, BATCH * SEQ, 1024, 1024, 1, nullptr, nullptr, nullptr, x, x2, nullptr,
      nullptr);

  transpose_k<<<dim3(4096 / 32, 1024 / 32), tb, 0, stream>>>(Wfc, wfcT, 1024, 4096);
  transpose_k<<<dim3(1024 / 32, 4096 / 32), tb, 0, stream>>>(Wp, wpT, 4096, 1024);

  ln_k<<<BATCH * SEQ, 256, 0, stream>>>(x2, ln2w, ln2b, qb);

  gemm_k<128><<<dim3(4096 / 128, 4096 / 128), 256, 0, stream>>>(
      qb, wfcT, bfc, BATCH * SEQ, 4096, 1024, 2, fcb, nullptr, nullptr, nullptr, nullptr,
      nullptr, nullptr);

  gemm_k<64><<<dim3(1024 / 128, 4096 / 64), 256, 0, stream>>>(
      fcb, wpT, bp, BATCH * SEQ, 1024, 4096, 3, nullptr, nullptr, nullptr, nullptr, nullptr, x2,
      outp);
}

// Round 4
// 404.502 us; speedup vs baseline: 1.0706x; 1.0706x over previous
//
#include <hip/hip_runtime.h>
#include <hip/hip_bf16.h>
#include <math.h>

using bf16 = __hip_bfloat16;
typedef __bf16 bf16x8 __attribute__((ext_vector_type(8)));
typedef float f32x4 __attribute__((ext_vector_type(4)));

#define SEQ 2048
#define DIM 1024
#define NH 16
#define HDIM 64
#define BATCH 2

// async global->LDS, 16B per lane; LDS dest = base + lane*16 (wave-uniform base)
__device__ __forceinline__ void load_lds16(const bf16* g, bf16* l) {
  __builtin_amdgcn_global_load_lds((__attribute__((address_space(1))) void*)g,
                                   (__attribute__((address_space(3))) void*)l, 16, 0, 0);
}

// ---------------- convert+transpose: in f32 [R][C] -> out bf16 [C][R] ----------------
__global__ __launch_bounds__(256) void transpose_k(const float* __restrict__ in,
                                                   bf16* __restrict__ out, int R, int C) {
  __shared__ float tile[32][33];
  int c0 = blockIdx.x * 32, r0 = blockIdx.y * 32;
  int tx = threadIdx.x, ty = threadIdx.y;  // (32,8)
#pragma unroll
  for (int j = 0; j < 4; ++j)
    tile[ty + 8 * j][tx] = in[(size_t)(r0 + ty + 8 * j) * C + c0 + tx];
  __syncthreads();
#pragma unroll
  for (int j = 0; j < 4; ++j)
    out[(size_t)(c0 + ty + 8 * j) * R + r0 + tx] = __float2bfloat16(tile[tx][ty + 8 * j]);
}

// ---------------- layernorm (torch-style: unbiased std, /(std+eps)); f32 in, bf16 out ----
__global__ __launch_bounds__(256) void ln_k(const float* __restrict__ x,
                                            const float* __restrict__ w,
                                            const float* __restrict__ bb,
                                            bf16* __restrict__ out) {
  int row = blockIdx.x, tid = threadIdx.x;
  int wid = tid >> 6, lane = tid & 63;
  const float* xr = x + (size_t)row * DIM;
  float v[4];
#pragma unroll
  for (int j = 0; j < 4; ++j) v[j] = xr[tid + 256 * j];
  float s = v[0] + v[1] + v[2] + v[3];
#pragma unroll
  for (int m = 1; m < 64; m <<= 1) s += __shfl_xor(s, m, 64);
  __shared__ float red[8];
  if (lane == 0) red[wid] = s;
  __syncthreads();
  float mean = (red[0] + red[1] + red[2] + red[3]) * (1.f / DIM);
  float q = 0.f;
#pragma unroll
  for (int j = 0; j < 4; ++j) {
    v[j] -= mean;
    q += v[j] * v[j];
  }
#pragma unroll
  for (int m = 1; m < 64; m <<= 1) q += __shfl_xor(q, m, 64);
  if (lane == 0) red[4 + wid] = q;
  __syncthreads();
  float ssq = red[4] + red[5] + red[6] + red[7];
  float sd = sqrtf(ssq / (float)(DIM - 1));
  float inv = 1.f / (sd + 1e-5f);
#pragma unroll
  for (int j = 0; j < 4; ++j) {
    int c = tid + 256 * j;
    float y = w[c] * (v[j] * inv) + bb[c];
    out[(size_t)row * DIM + c] = __float2bfloat16(y);
  }
}

// ============ 256x256-tile 8-wave phased GEMM: C[M,N] = A[M,K] @ Bt[N,K]^T + bias ============
// BK=64 split into two col-halves (ks). 4 phases per K-tile, 2 barriers/phase, counted
// vmcnt(8) only at ph1/ph3. Stage targets are always regions consumed >=1 barrier earlier:
//   ph0/ph1 stage A/B ks1-half of tile t+1 (other buffer, last read 2 phases ago)
//   ph2/ph3 stage A/B ks0-half of tile t+2 (this buffer, consumed in ph0/ph1)
// LDS swizzle: 16B-slot ^= ((row>>1)&3) on reads; inverse pre-applied to global source.
// mode 0: split qkv (q,k -> [B,H,S,HD]; v -> [B,H,HD,S]).  mode 2: o0 = gelu(acc+bias).
__global__ __launch_bounds__(512) void gemm256_k(
    const bf16* __restrict__ A, const bf16* __restrict__ Bt, const float* __restrict__ bias,
    int N, int K, int mode, bf16* __restrict__ o0, bf16* __restrict__ o1,
    bf16* __restrict__ o2) {
  __shared__ bf16 LDSb[65536];  // [buf][A ks0|ks1 16KB each][B ks0|ks1] = 128 KB
  int tid = threadIdx.x;
  int wid = tid >> 6, lane = tid & 63, quad = lane >> 4, l15 = lane & 15;
  int wm = wid >> 2, wn = wid & 3;  // 2M x 4N wave grid; per-wave out 128x64
  int m0 = blockIdx.y * 256, n0 = blockIdx.x * 256;
  int grow = lane >> 2;                       // row within 16-row chunk
  int gslot = (lane & 3) ^ ((lane >> 3) & 3); // pre-swizzled global 16B col-slot
  const int nt = K >> 6;

  // bias preload BEFORE any staging: oldest vmem, retires first, never perturbs vmcnt counts
  float bv[4];
#pragma unroll
  for (int nf = 0; nf < 4; ++nf) bv[nf] = bias[n0 + wn * 64 + nf * 16 + l15];

  auto stageA = [&](int tile, int ks) {
    int bd = tile & 1;
#pragma unroll
    for (int it = 0; it < 2; ++it) {
      int c = wid * 2 + it;  // 16 chunks of 16 rows x 32 cols (1KB) per col-half
      load_lds16(A + (size_t)(m0 + c * 16 + grow) * K + tile * 64 + ks * 32 + gslot * 8,
                 &LDSb[bd * 32768 + ks * 8192 + c * 512]);
    }
  };
  auto stageB = [&](int tile, int ks) {
    int bd = tile & 1;
#pragma unroll
    for (int it = 0; it < 2; ++it) {
      int c = wid * 2 + it;
      load_lds16(Bt + (size_t)(n0 + c * 16 + grow) * K + tile * 64 + ks * 32 + gslot * 8,
                 &LDSb[bd * 32768 + 16384 + ks * 8192 + c * 512]);
    }
  };

  f32x4 acc[8][4] = {};

  // prologue: tile0 both halves + tile1 ks0; wait oldest batch (tile0 ks0) landed
  stageA(0, 0); stageB(0, 0);
  stageA(0, 1); stageB(0, 1);
  stageA(1, 0); stageB(1, 0);
  asm volatile("s_waitcnt vmcnt(8)" ::: "memory");
  __builtin_amdgcn_sched_barrier(0);
  __builtin_amdgcn_s_barrier();
  __builtin_amdgcn_sched_barrier(0);

#define PHASE(BD, KS, MH, STAGE_STMT, WAIT_STMT)                                             \
  {                                                                                          \
    bf16x8 af[4], bq[4];                                                                     \
    _Pragma("unroll") for (int j = 0; j < 4; ++j) {                                          \
      int r = wm * 128 + (MH) * 64 + j * 16 + l15;                                           \
      af[j] = *(const bf16x8*)&LDSb[(BD) * 32768 + (KS) * 8192 + (r >> 4) * 512 +            \
                                    (r & 15) * 32 + ((quad ^ ((r >> 1) & 3)) << 3)];         \
    }                                                                                        \
    _Pragma("unroll") for (int n = 0; n < 4; ++n) {                                          \
      int r = wn * 64 + n * 16 + l15;                                                        \
      bq[n] = *(const bf16x8*)&LDSb[(BD) * 32768 + 16384 + (KS) * 8192 + (r >> 4) * 512 +    \
                                    (r & 15) * 32 + ((quad ^ ((r >> 1) & 3)) << 3)];         \
    }                                                                                        \
    STAGE_STMT;                                                                              \
    __builtin_amdgcn_sched_barrier(0);                                                       \
    __builtin_amdgcn_s_barrier();                                                            \
    __builtin_amdgcn_sched_barrier(0);                                                       \
    __builtin_amdgcn_s_setprio(1);                                                           \
    _Pragma("unroll") for (int j = 0; j < 4; ++j)                                            \
        _Pragma("unroll") for (int n = 0; n < 4; ++n)                                        \
            acc[(MH) * 4 + j][n] = __builtin_amdgcn_mfma_f32_16x16x32_bf16(                  \
                af[j], bq[n], acc[(MH) * 4 + j][n], 0, 0, 0);                                \
    __builtin_amdgcn_s_setprio(0);                                                           \
    WAIT_STMT;                                                                               \
    __builtin_amdgcn_sched_barrier(0);                                                       \
    __builtin_amdgcn_s_barrier();                                                            \
    __builtin_amdgcn_sched_barrier(0);                                                       \
  }

  for (int t = 0; t < nt; ++t) {
    int bd = t & 1;
    PHASE(bd, 0, 0, { if (t + 1 < nt) stageA(t + 1, 1); }, {});
    PHASE(bd, 0, 1, { if (t + 1 < nt) stageB(t + 1, 1); }, {
      if (t + 1 < nt) asm volatile("s_waitcnt vmcnt(8)" ::: "memory");
      else            asm volatile("s_waitcnt vmcnt(0)" ::: "memory");
    });
    PHASE(bd, 1, 0, { if (t + 2 < nt) stageA(t + 2, 0); }, {});
    PHASE(bd, 1, 1, { if (t + 2 < nt) stageB(t + 2, 0); }, {
      if (t + 2 < nt)      asm volatile("s_waitcnt vmcnt(8)" ::: "memory");
      else if (t + 1 < nt) asm volatile("s_waitcnt vmcnt(4)" ::: "memory");
    });
  }
#undef PHASE

#pragma unroll
  for (int mf = 0; mf < 8; ++mf) {
#pragma unroll
    for (int nf = 0; nf < 4; ++nf) {
      int col = n0 + wn * 64 + nf * 16 + l15;
      int row_base = m0 + wm * 128 + mf * 16 + quad * 4;
      if (mode == 0) {
        int which = col >> 10, d = col & 1023, hh = d >> 6, dd = d & 63;
        int b = row_base >> 11, s2 = row_base & 2047;
        if (which == 2) {
          unsigned short pk[4];
#pragma unroll
          for (int r = 0; r < 4; ++r)
            pk[r] = __bfloat16_as_ushort(__float2bfloat16(acc[mf][nf][r] + bv[nf]));
          *(uint2*)&o2[(((size_t)b * NH + hh) * HDIM + dd) * SEQ + s2] = *(uint2*)pk;
        } else {
          bf16* dst = which == 0 ? o0 : o1;
#pragma unroll
          for (int r = 0; r < 4; ++r)
            dst[(((size_t)b * NH + hh) * SEQ + s2 + r) * HDIM + dd] =
                __float2bfloat16(acc[mf][nf][r] + bv[nf]);
        }
      } else {
#pragma unroll
        for (int r = 0; r < 4; ++r) {
          float t2 = acc[mf][nf][r] + bv[nf];
          // gelu via sigmoid: 0.5t(1+tanh(u)) = t*sigmoid(2u)
          float u = 0.7978845608028654f * (t2 + 0.044715f * t2 * t2 * t2);
          float g = t2 / (1.f + __expf(-2.f * u));
          o0[(size_t)(row_base + r) * N + col] = __float2bfloat16(g);
        }
      }
    }
  }
}

// ---------------- GEMM (round-2 structure): 64x128 tile, single-buffered ----------------
// mode 1: x2out(f32) = residf(f32) + acc + bias
// mode 3: outf(f32) = x2in(f32) + acc + bias
template <int TM>
__global__ __launch_bounds__(256) void gemm_k(
    const bf16* __restrict__ A, const bf16* __restrict__ Bt, const float* __restrict__ bias,
    int M, int N, int K, int mode,
    const float* __restrict__ residf, float* __restrict__ x2out, const float* __restrict__ x2in,
    float* __restrict__ outf) {
  constexpr int MT = TM / 32;   // m-fragments per wave
  constexpr int ACH = TM / 8;   // 1KB staging chunks in A tile
  __shared__ bf16 As[TM * 64];
  __shared__ bf16 Bs[128 * 64];
  int tid = threadIdx.x;
  int wid = tid >> 6, lane = tid & 63, quad = lane >> 4, l15 = lane & 15;
  int wm = wid >> 1, wn = wid & 1;
  int m0 = blockIdx.y * TM, n0 = blockIdx.x * 128;
  int rsub = lane >> 3;          // row within an 8-row chunk
  int c8 = (lane & 7) ^ rsub;    // swizzled global column-chunk this lane fetches
  f32x4 acc[MT][4] = {};

  for (int k0 = 0; k0 < K; k0 += 64) {
    __syncthreads();
#pragma unroll
    for (int it = 0; it < ACH / 4; ++it) {
      int c = wid * (ACH / 4) + it;
      int row = c * 8 + rsub;
      load_lds16(A + (size_t)(m0 + row) * K + k0 + c8 * 8, &As[c * 512]);
    }
#pragma unroll
    for (int it = 0; it < 4; ++it) {
      int c = wid * 4 + it;
      int row = c * 8 + rsub;
      load_lds16(Bt + (size_t)(n0 + row) * K + k0 + c8 * 8, &Bs[c * 512]);
    }
    __syncthreads();  // drains vmcnt (global_load_lds) before use
#pragma unroll
    for (int ks = 0; ks < 2; ++ks) {
      bf16x8 af[MT], bfr[4];
#pragma unroll
      for (int mt = 0; mt < MT; ++mt) {
        int r = wm * (MT * 16) + mt * 16 + l15;
        af[mt] = *(const bf16x8*)&As[r * 64 + ((ks * 4 + quad) ^ (r & 7)) * 8];
      }
#pragma unroll
      for (int nt2 = 0; nt2 < 4; ++nt2) {
        int r = wn * 64 + nt2 * 16 + l15;
        bfr[nt2] = *(const bf16x8*)&Bs[r * 64 + ((ks * 4 + quad) ^ (r & 7)) * 8];
      }
#pragma unroll
      for (int mt = 0; mt < MT; ++mt)
#pragma unroll
        for (int nt2 = 0; nt2 < 4; ++nt2)
          acc[mt][nt2] =
              __builtin_amdgcn_mfma_f32_16x16x32_bf16(af[mt], bfr[nt2], acc[mt][nt2], 0, 0, 0);
    }
  }

#pragma unroll
  for (int mt = 0; mt < MT; ++mt) {
#pragma unroll
    for (int nt = 0; nt < 4; ++nt) {
      int col = n0 + wn * 64 + nt * 16 + l15;
      float bvs = bias[col];
      int row_base = m0 + wm * (MT * 16) + mt * 16 + quad * 4;
#pragma unroll
      for (int r = 0; r < 4; ++r) {
        int row = row_base + r;
        float val = acc[mt][nt][r] + bvs;
        size_t i = (size_t)row * N + col;
        if (mode == 1) x2out[i] = residf[i] + val;
        else           outf[i] = x2in[i] + val;
      }
    }
  }
}

// ---------------- V suffix-sum: suf[bh][d][q] = sum_{k>q} Vt[bh][d][k] (fp32) ----------------
__global__ __launch_bounds__(256) void sufv_k(const bf16* __restrict__ vt,
                                              float* __restrict__ suf) {
  int row = blockIdx.x;  // (b*NH+h)*HDIM + d
  const bf16* src = vt + (size_t)row * SEQ;
  float* dst = suf + (size_t)row * SEQ;
  int tid = threadIdx.x;
  float v[8];
  float s = 0.f;
#pragma unroll
  for (int j = 0; j < 8; ++j) {
    v[j] = __bfloat162float(src[tid * 8 + j]);
    s += v[j];
  }
  __shared__ float sc[256];
  sc[tid] = s;
  __syncthreads();
  for (int off = 1; off < 256; off <<= 1) {
    float add = (tid + off < 256) ? sc[tid + off] : 0.f;
    __syncthreads();
    sc[tid] += add;
    __syncthreads();
  }
  float run = (tid < 255) ? sc[tid + 1] : 0.f;  // exclusive suffix carry
#pragma unroll
  for (int j = 7; j >= 0; --j) {
    dst[tid * 8 + j] = run;
    run += v[j];
  }
}

// Ps swizzle: chunk ^ ((row&7) ^ (((row>>3)&1)<<1)) — bijective per row
__device__ __forceinline__ int pswz(int row) { return (row & 7) ^ (((row >> 3) & 1) << 1); }

// ---------------- attention: triangular, fixed-ref softmax, dbuf + swizzled, 4 blocks/CU ----
__global__ __launch_bounds__(256) void attn_k(const bf16* __restrict__ q,
                                              const bf16* __restrict__ k,
                                              const bf16* __restrict__ v,
                                              const int* __restrict__ rel,
                                              const float* __restrict__ rel_emb,
                                              const float* __restrict__ suf,
                                              bf16* __restrict__ out) {
  int h = blockIdx.x;
  int qt = (SEQ / 64 - 1) - blockIdx.y;  // heavy blocks first
  int b = blockIdx.z;
  int tid = threadIdx.x;
  int wid = tid >> 6, lane = tid & 63, quad = lane >> 4, l15 = lane & 15;

  __shared__ __align__(16) char SM[40960];
  bf16* Kb = (bf16*)SM;                        // [2][64][64] swizzled chunks
  bf16* Vb = (bf16*)(SM + 16384);              // [2][64][64] swizzled ([d][key])
  bf16* Ps = (bf16*)(SM + 32768);              // [64][64] swizzled
  float(*SufLds)[68] = (float(*)[68])SM;       // epilogue alias over K/V dbuf (17408 B)

  const size_t bh = (size_t)b * NH + h;
  const bf16* qb = q + (bh * SEQ + (size_t)qt * 64) * HDIM;
  const bf16* kb0 = k + bh * SEQ * HDIM;
  const bf16* vt0 = v + bh * (size_t)HDIM * SEQ;

  float rv = 0.125f * rel_emb[lane * NH + h];

  int rsub = lane >> 3;
  int c8 = (lane & 7) ^ rsub;  // pre-swizzled source chunk -> linear LDS dest

  bf16x8 aq[2];
#pragma unroll
  for (int ks = 0; ks < 2; ++ks)
    aq[ks] = *(const bf16x8*)(qb + (size_t)(wid * 16 + l15) * HDIM + ks * 32 + quad * 8);

#pragma unroll
  for (int it = 0; it < 2; ++it) {
    int c = wid * 2 + it;
    int row = c * 8 + rsub;
    load_lds16(kb0 + (size_t)row * HDIM + c8 * 8, &Kb[c * 512]);
    load_lds16(vt0 + (size_t)row * SEQ + c8 * 8, &Vb[c * 512]);
  }

  const int* relq = rel + (size_t)b * SEQ * SEQ + (size_t)qt * 64 * SEQ;
  const int* rp[4];
#pragma unroll
  for (int r = 0; r < 4; ++r) rp[r] = relq + (size_t)(wid * 16 + quad * 4 + r) * SEQ;

  int ridx[4][4];
#pragma unroll
  for (int nt = 0; nt < 4; ++nt)
#pragma unroll
    for (int r = 0; r < 4; ++r) ridx[nt][r] = rp[r][nt * 16 + l15];

  __syncthreads();  // drain prologue staging

  const int q_base = qt * 64 + wid * 16 + quad * 4;
  const int prow_w = wid * 16 + quad * 4;
  const int prow_r = wid * 16 + l15;
  const int psw_r = pswz(prow_r);
  float l_part[4] = {0.f, 0.f, 0.f, 0.f};
  f32x4 o_acc[4] = {};

  for (int kt = 0; kt < qt; ++kt) {
    int cur = kt & 1;
    int ridx2[4][4];
    {
      bf16* Kd = Kb + (cur ^ 1) * 4096;
      bf16* Vd = Vb + (cur ^ 1) * 4096;
#pragma unroll
      for (int it = 0; it < 2; ++it) {
        int c = wid * 2 + it;
        int row = c * 8 + rsub;
        load_lds16(kb0 + (size_t)((kt + 1) * 64 + row) * HDIM + c8 * 8, &Kd[c * 512]);
        load_lds16(vt0 + (size_t)row * SEQ + (kt + 1) * 64 + c8 * 8, &Vd[c * 512]);
      }
#pragma unroll
      for (int nt = 0; nt < 4; ++nt)
#pragma unroll
        for (int r = 0; r < 4; ++r) ridx2[nt][r] = rp[r][(kt + 1) * 64 + nt * 16 + l15];
    }

    const bf16* Ksb = Kb + cur * 4096;
    const bf16* Vtb = Vb + cur * 4096;

    f32x4 sacc[4] = {};
    __builtin_amdgcn_s_setprio(1);
#pragma unroll
    for (int ks = 0; ks < 2; ++ks) {
#pragma unroll
      for (int nt = 0; nt < 4; ++nt) {
        bf16x8 bfr = *(const bf16x8*)&Ksb[(nt * 16 + l15) * 64 + ((ks * 4 + quad) ^ (l15 & 7)) * 8];
        sacc[nt] = __builtin_amdgcn_mfma_f32_16x16x32_bf16(aq[ks], bfr, sacc[nt], 0, 0, 0);
      }
    }
    __builtin_amdgcn_s_setprio(0);

#pragma unroll
    for (int nt = 0; nt < 4; ++nt) {
#pragma unroll
      for (int r = 0; r < 4; ++r) {
        float m = __shfl(rv, ridx[nt][r], 64);
        float p = __expf(sacc[nt][r] * m);
        l_part[r] += p;
        int row = prow_w + r;
        int sw = (nt * 2 + (l15 >> 3)) ^ pswz(row);
        Ps[row * 64 + sw * 8 + (l15 & 7)] = __float2bfloat16(p);
      }
    }

    __builtin_amdgcn_s_setprio(1);
#pragma unroll
    for (int ks = 0; ks < 2; ++ks) {
      bf16x8 af = *(const bf16x8*)&Ps[prow_r * 64 + ((ks * 4 + quad) ^ psw_r) * 8];
#pragma unroll
      for (int nt = 0; nt < 4; ++nt) {
        bf16x8 bfr = *(const bf16x8*)&Vtb[(nt * 16 + l15) * 64 + ((ks * 4 + quad) ^ (l15 & 7)) * 8];
        o_acc[nt] = __builtin_amdgcn_mfma_f32_16x16x32_bf16(af, bfr, o_acc[nt], 0, 0, 0);
      }
    }
    __builtin_amdgcn_s_setprio(0);

    __syncthreads();

#pragma unroll
    for (int nt = 0; nt < 4; ++nt)
#pragma unroll
      for (int r = 0; r < 4; ++r) ridx[nt][r] = ridx2[nt][r];
  }

  // diagonal tile
  {
    int cur = qt & 1;
    const bf16* Ksb = Kb + cur * 4096;
    const bf16* Vtb = Vb + cur * 4096;

    f32x4 sacc[4] = {};
    __builtin_amdgcn_s_setprio(1);
#pragma unroll
    for (int ks = 0; ks < 2; ++ks) {
#pragma unroll
      for (int nt = 0; nt < 4; ++nt) {
        bf16x8 bfr = *(const bf16x8*)&Ksb[(nt * 16 + l15) * 64 + ((ks * 4 + quad) ^ (l15 & 7)) * 8];
        sacc[nt] = __builtin_amdgcn_mfma_f32_16x16x32_bf16(aq[ks], bfr, sacc[nt], 0, 0, 0);
      }
    }
    __builtin_amdgcn_s_setprio(0);

#pragma unroll
    for (int nt = 0; nt < 4; ++nt) {
#pragma unroll
      for (int r = 0; r < 4; ++r) {
        float m = __shfl(rv, ridx[nt][r], 64);
        float p = __expf(sacc[nt][r] * m);
        int k_abs = qt * 64 + nt * 16 + l15;
        if (k_abs > q_base + r) p = 0.f;
        l_part[r] += p;
        int row = prow_w + r;
        int sw = (nt * 2 + (l15 >> 3)) ^ pswz(row);
        Ps[row * 64 + sw * 8 + (l15 & 7)] = __float2bfloat16(p);
      }
    }

    __builtin_amdgcn_s_setprio(1);
#pragma unroll
    for (int ks = 0; ks < 2; ++ks) {
      bf16x8 af = *(const bf16x8*)&Ps[prow_r * 64 + ((ks * 4 + quad) ^ psw_r) * 8];
#pragma unroll
      for (int nt = 0; nt < 4; ++nt) {
        bf16x8 bfr = *(const bf16x8*)&Vtb[(nt * 16 + l15) * 64 + ((ks * 4 + quad) ^ (l15 & 7)) * 8];
        o_acc[nt] = __builtin_amdgcn_mfma_f32_16x16x32_bf16(af, bfr, o_acc[nt], 0, 0, 0);
      }
    }
    __builtin_amdgcn_s_setprio(0);

    __syncthreads();
  }

#pragma unroll
  for (int r = 0; r < 4; ++r)
#pragma unroll
    for (int m = 1; m < 16; m <<= 1) l_part[r] += __shfl_xor(l_part[r], m, 64);

  const float* sufb = suf + bh * (size_t)HDIM * SEQ + (size_t)qt * 64;
#pragma unroll
  for (int p = 0; p < 4; ++p) {
    int idx = p * 256 + tid;
    int d = idx >> 4, qq = idx & 15;
    *(float4*)&SufLds[d][qq * 4] = *(const float4*)(sufb + (size_t)d * SEQ + qq * 4);
  }
  __syncthreads();

#pragma unroll
  for (int nt = 0; nt < 4; ++nt) {
    int d = nt * 16 + l15;
#pragma unroll
    for (int r = 0; r < 4; ++r) {
      int row = q_base + r;
      int cnt = (SEQ - 1) - row;
      float l = l_part[r] + (float)cnt;
      int q_local = wid * 16 + quad * 4 + r;
      float ov = (o_acc[nt][r] + SufLds[d][q_local]) / l;
      out[((size_t)b * SEQ + row) * DIM + h * HDIM + d] = __float2bfloat16(ov);
    }
  }
}

// ---------------- launcher ----------------
extern "C" void kernel_launch(void* const* d_in, const int* in_sizes, int n_in,
                              void* d_out, int out_size, void* d_ws, size_t ws_size,
                              hipStream_t stream) {
  const float* x = (const float*)d_in[0];
  const int* rel = (const int*)d_in[1];
  const float* ln1w = (const float*)d_in[2];
  const float* ln1b = (const float*)d_in[3];
  const float* Wqkv = (const float*)d_in[4];
  const float* bqkv = (const float*)d_in[5];
  const float* Wo = (const float*)d_in[6];
  const float* bo = (const float*)d_in[7];
  const float* rel_emb = (const float*)d_in[8];
  const float* ln2w = (const float*)d_in[9];
  const float* ln2b = (const float*)d_in[10];
  const float* Wfc = (const float*)d_in[11];
  const float* bfc = (const float*)d_in[12];
  const float* Wp = (const float*)d_in[13];
  const float* bp = (const float*)d_in[14];
  float* outp = (float*)d_out;  // reference output dtype is float32

  char* ws = (char*)d_ws;
  const size_t MB = 1u << 20;
  bf16* h = (bf16*)(ws + 0);           // ln1 out -> attn out
  bf16* qb = (bf16*)(ws + 8 * MB);     // q -> ln2 out
  bf16* kb = (bf16*)(ws + 16 * MB);    // k -> wfcT
  bf16* vb = (bf16*)(ws + 24 * MB);    // v transposed [B,H,HD,S] -> wpT
  float* x2 = (float*)(ws + 32 * MB);  // early: V suffix-sums; later: residual stream
  float* suf = (float*)(ws + 32 * MB);
  bf16* fcb = (bf16*)(ws + 48 * MB);   // gelu(fc); early: wqkvT@48, woT@54
  bf16* wqkvT = (bf16*)(ws + 48 * MB);
  bf16* woT = (bf16*)(ws + 54 * MB);
  bf16* wfcT = (bf16*)(ws + 16 * MB);
  bf16* wpT = (bf16*)(ws + 24 * MB);

  dim3 tb(32, 8);
  transpose_k<<<dim3(3072 / 32, 1024 / 32), tb, 0, stream>>>(Wqkv, wqkvT, 1024, 3072);
  transpose_k<<<dim3(1024 / 32, 1024 / 32), tb, 0, stream>>>(Wo, woT, 1024, 1024);

  ln_k<<<BATCH * SEQ, 256, 0, stream>>>(x, ln1w, ln1b, h);

  gemm256_k<<<dim3(3072 / 256, 4096 / 256), 512, 0, stream>>>(
      h, wqkvT, bqkv, 3072, 1024, 0, qb, kb, vb);

  sufv_k<<<BATCH * NH * HDIM, 256, 0, stream>>>(vb, suf);

  attn_k<<<dim3(NH, SEQ / 64, BATCH), 256, 0, stream>>>(qb, kb, vb, rel, rel_emb, suf, h);

  gemm_k<64><<<dim3(1024 / 128, 4096 / 64), 256, 0, stream>>>(
      h, woT, bo, BATCH * SEQ, 1024, 1024, 1, x, x2, nullptr, nullptr);

  transpose_k<<<dim3(4096 / 32, 1024 / 32), tb, 0, stream>>>(Wfc, wfcT, 1024, 4096);
  transpose_k<<<dim3(1024 / 32, 4096 / 32), tb, 0, stream>>>(Wp, wpT, 4096, 1024);

  ln_k<<<BATCH * SEQ, 256, 0, stream>>>(x2, ln2w, ln2b, qb);

  gemm256_k<<<dim3(4096 / 256, 4096 / 256), 512, 0, stream>>>(
      qb, wfcT, bfc, 4096, 1024, 2, fcb, nullptr, nullptr);

  gemm_k<64><<<dim3(1024 / 128, 4096 / 64), 256, 0, stream>>>(
      fcb, wpT, bp, BATCH * SEQ, 1024, 4096, 3, nullptr, nullptr, x2, outp);
}